// Round 18
// baseline (19278.210 us; speedup 1.0000x reference)
//
#include <hip/hip_runtime.h>
#include <hip/hip_fp16.h>
#include <math.h>

#define N 1024
#define M 2048
#define C 64
#define NB 128
#define TB 8    // N/NB
#define NBLK 36                   // TB*(TB+1)/2 lower-tri blocks
#define PL ((size_t)NBLK*NB*NB)   // packed L floats per chain

typedef __attribute__((ext_vector_type(8))) short bf16x8;
typedef __attribute__((ext_vector_type(8))) _Float16 f16x8;
typedef __attribute__((ext_vector_type(4))) float f32x4;

__device__ __forceinline__ size_t pblk(int ib, int jt){
    return ((size_t)((ib*(ib+1))/2 + jt))*((size_t)NB*NB);
}

// rotate-swizzle for the in-LDS factor: bank=(r+c)%32
#define TT(r,c) T[(r)][(((c)+(r)) & 127)]

// ---------------- helpers ----------------

__device__ __forceinline__ float sqdist4(const float4 a, const float4 b){
    float dx=a.x-b.x, dy=a.y-b.y, dz=a.z-b.z, dw=a.w-b.w;
    return dx*dx+dy*dy+dz*dz+dw*dw;
}

// split 4 floats into bf16 hi (trunc) + bf16 lo (residual), packed 2/dword
__device__ __forceinline__ void split4(float x0, float x1, float x2, float x3,
                                       uint2& hi, uint2& lo){
    unsigned b0=__float_as_uint(x0), b1=__float_as_uint(x1),
             b2=__float_as_uint(x2), b3=__float_as_uint(x3);
    unsigned h0=b0&0xFFFF0000u, h1=b1&0xFFFF0000u, h2=b2&0xFFFF0000u, h3=b3&0xFFFF0000u;
    hi.x = (h0>>16)|h1;  hi.y = (h2>>16)|h3;
    float l0=x0-__uint_as_float(h0), l1=x1-__uint_as_float(h1),
          l2=x2-__uint_as_float(h2), l3=x3-__uint_as_float(h3);
    lo.x = (__float_as_uint(l0)>>16) | (__float_as_uint(l1)&0xFFFF0000u);
    lo.y = (__float_as_uint(l2)>>16) | (__float_as_uint(l3)&0xFFFF0000u);
}

// Conflict-free in-LDS Cholesky + triangular inversion of a 128x128 block.
__device__ void chol_invert_lds(float T[NB][NB], int tid){
    for (int j = 0; j < NB; j++){
        float d = TT(j,j);
        float inv = 1.0f / sqrtf(d);
        for (int i = j+1+tid; i < NB; i += 256) TT(i,j) *= inv;
        if (tid == 0) TT(j,j) = d * inv;
        __syncthreads();
        int i = j+1 + (tid >> 1);
        if (i < NB){
            float lij = TT(i,j);
            for (int k = j+1+(tid&1); k <= i; k += 2)
                TT(i,k) -= lij * TT(k,j);
        }
        __syncthreads();
    }
    for (int i = 0; i < NB; i++){
        float inv_ii = 1.0f / TT(i,i);
        int j = tid & 127, hi = tid >> 7;
        float S = 0.0f;
        if (j < i){
            for (int k = i-1-hi; k >= j; k -= 2)
                S += TT(i,k) * TT(k,j);
        }
        if (hi && j < i) TT(j,i) = S;
        __syncthreads();
        if (!hi){
            if (j < i)      TT(i,j) = -inv_ii * (S + TT(j,i));
            else if (j == i) TT(i,i) = inv_ii;
        }
        __syncthreads();
    }
}

// ---------------- split-f16 MFMA 128x128x128 GEMM core ----------------

struct FragLds { __half Ah[4096], Al[4096], Bh[4096], Bl[4096]; }; // 32 KiB
struct SmX { float4 xr[NB]; float4 xc[NB]; };                      // 4 KiB
union SmU { FragLds f; float T[NB][NB]; SmX x; };                  // 64 KiB

__device__ __forceinline__ void stage_f16(__half* __restrict__ Hh, __half* __restrict__ Hl,
                                          const float* __restrict__ S, int ld,
                                          int k0, bool contig, int tid){
    #pragma unroll
    for (int h = 0; h < 2; h++){
        int u = tid + h*256;
        int fr = u & 15, kg = (u>>4)&3, rt = (u>>6)&3, hf = u>>8;
        int rc = hf*64 + rt*16 + fr;
        int kk = k0 + kg*8;
        float x[8];
        if (contig){
            float4 v0 = *(const float4*)&S[(size_t)rc*ld + kk];
            float4 v1 = *(const float4*)&S[(size_t)rc*ld + kk + 4];
            x[0]=v0.x;x[1]=v0.y;x[2]=v0.z;x[3]=v0.w;
            x[4]=v1.x;x[5]=v1.y;x[6]=v1.z;x[7]=v1.w;
        } else {
            #pragma unroll
            for (int e=0;e<8;e++) x[e] = S[(size_t)(kk+e)*ld + rc];
        }
        union { __half h[8]; uint4 u4; } Hi, Lo;
        #pragma unroll
        for (int e=0;e<8;e++){
            __half hv = __float2half_rn(x[e]);
            Hi.h[e] = hv;
            Lo.h[e] = __float2half_rn(x[e] - __half2float(hv));
        }
        *(uint4*)&Hh[(size_t)u*8] = Hi.u4;
        *(uint4*)&Hl[(size_t)u*8] = Lo.u4;
    }
}

__device__ __forceinline__ void mfma_slab_f16(const __half* Ah, const __half* Al,
                                              const __half* Bh, const __half* Bl,
                                              int wrow, int wcol, int lane,
                                              f32x4 acc[4][4]){
    f16x8 ah[4], al[4];
    #pragma unroll
    for (int rt=0;rt<4;rt++){
        ah[rt] = *(const f16x8*)&Ah[((size_t)((wrow*4+rt)*64 + lane))*8];
        al[rt] = *(const f16x8*)&Al[((size_t)((wrow*4+rt)*64 + lane))*8];
    }
    #pragma unroll
    for (int ct=0;ct<4;ct++){
        f16x8 bh = *(const f16x8*)&Bh[((size_t)((wcol*4+ct)*64 + lane))*8];
        f16x8 bl = *(const f16x8*)&Bl[((size_t)((wcol*4+ct)*64 + lane))*8];
        #pragma unroll
        for (int rt=0;rt<4;rt++){
            f32x4 a = acc[rt][ct];
            a = __builtin_amdgcn_mfma_f32_16x16x32_f16(ah[rt], bh, a, 0,0,0);
            a = __builtin_amdgcn_mfma_f32_16x16x32_f16(ah[rt], bl, a, 0,0,0);
            a = __builtin_amdgcn_mfma_f32_16x16x32_f16(al[rt], bh, a, 0,0,0);
            acc[rt][ct] = a;
        }
    }
}

__device__ void gemm_f16_unit(const float* __restrict__ A, int lda,
                              const float* __restrict__ B, int ldb, bool bContig,
                              FragLds& F, f32x4 acc[4][4], int tid){
    int lane = tid & 63, w = tid >> 6, wrow = w>>1, wcol = w&1;
    for (int k0 = 0; k0 < NB; k0 += 32){
        __syncthreads();
        stage_f16(F.Ah, F.Al, A, lda, k0, true, tid);
        stage_f16(F.Bh, F.Bl, B, ldb, k0, bContig, tid);
        __syncthreads();
        mfma_slab_f16(F.Ah, F.Al, F.Bh, F.Bl, wrow, wcol, lane, acc);
    }
}

// D-layout store: row = wrow*64+rt*16+kg*4+r, col = wcol*64+ct*16+fr
__device__ __forceinline__ void store_f16acc(float* __restrict__ Cp, int ldc,
                                             const f32x4 acc[4][4], float sgn, int tid){
    int lane = tid&63, w = tid>>6, wrow = w>>1, wcol = w&1;
    int fr = lane&15, kg = lane>>4;
    #pragma unroll
    for (int rt=0;rt<4;rt++)
      #pragma unroll
      for (int ct=0;ct<4;ct++)
        #pragma unroll
        for (int r=0;r<4;r++){
            int row = wrow*64 + rt*16 + kg*4 + r;
            int col = wcol*64 + ct*16 + fr;
            Cp[(size_t)row*ldc + col] = sgn*acc[rt][ct][r];
        }
}

#define ZERO_ACC(acc) { _Pragma("unroll") for (int zi=0;zi<4;zi++) _Pragma("unroll") for (int zj=0;zj<4;zj++) acc[zi][zj] = (f32x4)0.0f; }

// ---------------- kernels ----------------

__global__ void k_init_acc(float* __restrict__ acc){
    int i = blockIdx.x*blockDim.x + threadIdx.x;
    if (i < 2*M) acc[i] = 0.0f;
}

// d2te[j][i] = ||Xte_j - Xtr_i||^2   (M x N)
__global__ void k_build_d2te(const float* __restrict__ Xtr, const float* __restrict__ Xte,
                             float* __restrict__ d2){
    int j = blockIdx.x;
    float4 xj = ((const float4*)Xte)[j];
    for (int i = threadIdx.x; i < N; i += blockDim.x){
        float4 xi = ((const float4*)Xtr)[i];
        d2[(size_t)j*N + i] = sqdist4(xi,xj);
    }
}

__global__ void k_final(const float* __restrict__ acc, float* __restrict__ out){
    int i = blockIdx.x*blockDim.x + threadIdx.x;
    if (i < 2*M) out[i] = acc[i] * (1.0f/64.0f);
}

// Build packed lower-tri blocks of K_noisy. grid (NBLK, g).
// flat==0 block additionally factors+inverts the (0,0) diag block in LDS.
// flat<TB blocks zero their zbuf segment (consumed by k_wsplit's z-dot).
__global__ __launch_bounds__(256) void k_build_K(const float* __restrict__ Xtr,
                          const float* __restrict__ ls,
                          const float* __restrict__ var, const float* __restrict__ noise,
                          float* __restrict__ Lbuf, float* __restrict__ zbuf){
    __shared__ SmU sm;
    int c = blockIdx.y, flat = blockIdx.x;
    int ib = 0; while ((ib+1)*(ib+2)/2 <= flat) ib++;
    int jt = flat - ib*(ib+1)/2;
    int tid = threadIdx.x;
    if (flat < TB && tid < NB) zbuf[c*N + flat*NB + tid] = 0.0f;
    if (tid < NB) sm.x.xr[tid] = ((const float4*)Xtr)[ib*NB + tid];
    else          sm.x.xc[tid-NB] = ((const float4*)Xtr)[jt*NB + (tid-NB)];
    __syncthreads();
    float il2 = 1.0f/(ls[c]*ls[c]);
    float vc = var[c], nc = noise[c];
    float* blk = Lbuf + c*PL + pblk(ib,jt);
    for (int idx = tid; idx < NB*NB; idx += 256){
        int r = idx >> 7, col = idx & 127;
        float d2v = sqdist4(sm.x.xr[r], sm.x.xc[col]);
        float v = vc*__expf(-0.5f*d2v*il2);
        if (ib==jt && r==col) v += nc;
        blk[idx] = v;
    }
    if (flat == 0){
        // block-local global RAW (visible after syncthreads), then factor in LDS
        __threadfence_block();
        __syncthreads();            // xr/xc dead; union reuse as T
        float (*T)[NB] = sm.T;
        for (int idx = tid; idx < NB*NB; idx += 256){
            int r = idx >> 7, col = idx & 127;
            TT(r,col) = blk[idx];
        }
        __syncthreads();
        chol_invert_lds(T, tid);
        for (int idx = tid; idx < NB*NB; idx += 256){
            int r = idx >> 7, col = idx & 127;
            blk[idx] = (col <= r) ? TT(r,col) : 0.0f;
        }
    }
}

// panel TRSM as GEMM: L[ib,kb] = L[ib,kb] @ Dinv_kb^T   (split-f16 MFMA, in place)
__global__ __launch_bounds__(256) void k_panel(float* __restrict__ Lbuf, int kb){
    __shared__ FragLds F;
    int c = blockIdx.x;
    int ib = kb + 1 + blockIdx.y;
    int tid = threadIdx.x;
    float* base = Lbuf + (size_t)c*PL;
    float* Ablk = base + pblk(ib,kb);
    const float* Dv = base + pblk(kb,kb);
    f32x4 acc[4][4]; ZERO_ACC(acc);
    gemm_f16_unit(Ablk, NB, Dv, NB, true, F, acc, tid);   // B[c][k]=Dinv[c][k]
    store_f16acc(Ablk, NB, acc, 1.0f, tid);
}

// trailing update K[i,j] -= P_i @ P_j^T; flat==0 block also factors+inverts
__global__ __launch_bounds__(256) void k_syrk(float* __restrict__ Lbuf, int kb){
    __shared__ SmU sm;
    int c = blockIdx.x;
    int flat = blockIdx.y;
    int di = 0; while ((di+1)*(di+2)/2 <= flat) di++;
    int dj = flat - di*(di+1)/2;
    int i = kb+1+di, j = kb+1+dj;
    int tid = threadIdx.x;
    float* base = Lbuf + (size_t)c*PL;
    float* Cblk = base + pblk(i,j);
    const float* Ablk = base + pblk(i,kb);
    const float* Bblk = base + pblk(j,kb);
    f32x4 acc[4][4]; ZERO_ACC(acc);
    gemm_f16_unit(Ablk, NB, Bblk, NB, true, sm.f, acc, tid);  // B[c][k]=L[j,kb][c][k]
    int lane = tid&63, w = tid>>6, wrow = w>>1, wcol = w&1;
    int fr = lane&15, kg = lane>>4;
    if (flat != 0){
        #pragma unroll
        for (int rt=0;rt<4;rt++)
          #pragma unroll
          for (int ct=0;ct<4;ct++)
            #pragma unroll
            for (int r=0;r<4;r++){
                int row = wrow*64 + rt*16 + kg*4 + r;
                int col = wcol*64 + ct*16 + fr;
                Cblk[(size_t)row*NB + col] -= acc[rt][ct][r];
            }
    } else {
        __syncthreads();   // frag LDS reads done; reuse as T
        float (*T)[NB] = sm.T;
        #pragma unroll
        for (int rt=0;rt<4;rt++)
          #pragma unroll
          for (int ct=0;ct<4;ct++)
            #pragma unroll
            for (int r=0;r<4;r++){
                int row = wrow*64 + rt*16 + kg*4 + r;
                int col = wcol*64 + ct*16 + fr;
                TT(row,col) = Cblk[(size_t)row*NB + col] - acc[rt][ct][r];
            }
        __syncthreads();
        chol_invert_lds(T, tid);
        for (int idx = tid; idx < NB*NB; idx += 256){
            int r = idx >> 7, col = idx & 127;
            Cblk[idx] = (col <= r) ? TT(r,col) : 0.0f;
        }
    }
}

// G(ct) = Dinv_ib @ L[ib,ct]   (snapshot of row ib into Trow; race-free)
__global__ __launch_bounds__(256) void k_gemmA(float* __restrict__ Trow,
                                               const float* __restrict__ Lbuf, int ib){
    __shared__ FragLds F;
    int c = blockIdx.x, ct = blockIdx.y;
    int tid = threadIdx.x;
    const float* base = Lbuf + (size_t)c*PL;
    const float* Dv = base + pblk(ib,ib);
    const float* Bsrc = base + pblk(ib,ct);
    f32x4 acc[4][4]; ZERO_ACC(acc);
    gemm_f16_unit(Dv, NB, Bsrc, NB, false, F, acc, tid);  // B[k][c] strided
    store_f16acc(Trow + (size_t)c*NB*N + ct*NB, N, acc, 1.0f, tid);
}

// W[ib,jt] = - sum_{kt=jt..ib-1} G[:,kt] @ W[kt,jt]   (reads Trow + rows < ib)
__global__ __launch_bounds__(256) void k_gemmB(float* __restrict__ Lbuf,
                                               const float* __restrict__ Trow, int ib){
    __shared__ FragLds F;
    int c = blockIdx.x, jt = blockIdx.y;
    int tid = threadIdx.x;
    const float* G = Trow + (size_t)c*NB*N;
    float* base = Lbuf + (size_t)c*PL;
    f32x4 acc[4][4]; ZERO_ACC(acc);
    for (int kt = jt; kt < ib; kt++)
        gemm_f16_unit(G + kt*NB, N, base + pblk(kt,jt), NB, false, F, acc, tid);
    store_f16acc(base + pblk(ib,jt), NB, acc, -1.0f, tid);
}

// Fused inversion step: blocks y<ib run gemmB(ib) (read Trd, write row ib);
// blocks y>=ib run gemmA(ib+1) (read row ib+1 + diag ib+1, write Twr).
// Race-free: row ib (written) disjoint from row ib+1 + diag (read);
// Trd (read) and Twr (written) are separate ping-pong buffers.
__global__ __launch_bounds__(256) void k_invAB(float* __restrict__ Lbuf,
                                               const float* __restrict__ Trd,
                                               float* __restrict__ Twr, int ib){
    __shared__ FragLds F;
    int c = blockIdx.x, y = blockIdx.y;
    int tid = threadIdx.x;
    float* base = Lbuf + (size_t)c*PL;
    f32x4 acc[4][4]; ZERO_ACC(acc);
    if (y < ib){
        int jt = y;
        const float* G = Trd + (size_t)c*NB*N;
        for (int kt = jt; kt < ib; kt++)
            gemm_f16_unit(G + kt*NB, N, base + pblk(kt,jt), NB, false, F, acc, tid);
        store_f16acc(base + pblk(ib,jt), NB, acc, -1.0f, tid);
    } else {
        int ct = y - ib;
        const float* Dv = base + pblk(ib+1,ib+1);
        const float* Bsrc = base + pblk(ib+1,ct);
        gemm_f16_unit(Dv, NB, Bsrc, NB, false, F, acc, tid);
        store_f16acc(Twr + (size_t)c*NB*N + ct*NB, N, acc, 1.0f, tid);
    }
}

// Per W block: (1) z-partial: z[pb*128+row] += W_block_row . y[kt*128..]
// (full 128-wide dot is exact: diag blocks store zero upper), then
// (2) convert block IN PLACE to fragment-order split-bf16 images
// [slab 0..3][hi/lo][512 units][8 shorts].
__global__ __launch_bounds__(256) void k_wsplit(float* __restrict__ Lbuf,
                                                const float* __restrict__ ytr,
                                                float* __restrict__ zbuf){
    int c = blockIdx.y, flat = blockIdx.x;
    int pb = 0; while ((pb+1)*(pb+2)/2 <= flat) pb++;
    int kt = flat - pb*(pb+1)/2;
    int tid = threadIdx.x;
    float* blk = Lbuf + c*PL + (size_t)flat*NB*NB;
    // --- z-dot (reads f32 block before overwrite) ---
    {
        int row = tid >> 1, half = tid & 1;
        const float* wp = blk + (size_t)row*NB + half*64;
        const float* yp = ytr + kt*NB + half*64;
        float s = 0.0f;
        for (int i = 0; i < 64; i++) s += wp[i]*yp[i];
        s += __shfl_xor(s, 1);
        if (!half) atomicAdd(&zbuf[c*N + pb*NB + row], s);
    }
    // --- in-place split (register staged; barrier separates reads/writes) ---
    float4 v[16];
    #pragma unroll
    for (int h = 0; h < 8; h++){
        int g = tid + h*256;           // unit-global 0..2047
        int u = g & 511, slab = g >> 9;
        int fr = u&15, kg = (u>>4)&3, rt = (u>>6)&3, hf = u>>8;
        int row = hf*64 + rt*16 + fr;
        int k = slab*32 + kg*8;
        v[2*h]   = *(const float4*)&blk[(size_t)row*NB + k];
        v[2*h+1] = *(const float4*)&blk[(size_t)row*NB + k + 4];
    }
    __syncthreads();
    unsigned short* out = (unsigned short*)blk;
    #pragma unroll
    for (int h = 0; h < 8; h++){
        int g = tid + h*256;
        int u = g & 511, slab = g >> 9;
        uint2 h0, l0, h1, l1;
        split4(v[2*h].x, v[2*h].y, v[2*h].z, v[2*h].w, h0, l0);
        split4(v[2*h+1].x, v[2*h+1].y, v[2*h+1].z, v[2*h+1].w, h1, l1);
        *(uint4*)&out[((size_t)(slab*2+0)*512 + u)*8] = make_uint4(h0.x,h0.y,h1.x,h1.y);
        *(uint4*)&out[((size_t)(slab*2+1)*512 + u)*8] = make_uint4(l0.x,l0.y,l1.x,l1.y);
    }
}

// Fused A = Kte @ W^T via split-bf16 MFMA.  A: exp-only staging to LDS
// (vc folded into epilogue); B: coalesced 16B LDS copies of pre-split
// fragment images.  Grid x = 128 flat (jt,pt):
//   jt = flat&15, pt = ((flat>>4) + (jt&7)) & 7
// acc_out[0..M)=mean, [M..2M)=var.
__global__ __launch_bounds__(256) void k_bigg(const float* __restrict__ Lbuf,
                                              const float* __restrict__ d2,   // [M][N]
                                              const float* __restrict__ zbuf,
                                              const float* __restrict__ ls,
                                              const float* __restrict__ var,
                                              float* __restrict__ acc_out){
    __shared__ unsigned short Ah[4096], Al[4096], Bh[4096], Bl[4096];  // 32 KiB
    int flat = blockIdx.x, c = blockIdx.y;
    int jt = flat & 15;
    int pt = ((flat >> 4) + (jt & 7)) & 7;
    int tid = threadIdx.x;
    int lane = tid & 63, w = tid >> 6;
    int wrow = w >> 1, wcol = w & 1;
    float il2 = 1.0f/(ls[c]*ls[c]);
    float vc = var[c];
    float ec = -0.5f*il2;
    const float* Arow = d2 + (size_t)(jt*NB)*N;
    const float* Wbase = Lbuf + (size_t)c*PL;
    int klen = (pt+1)*NB;
    f32x4 acc[4][4]; ZERO_ACC(acc);

    int fr = lane & 15, kg = lane >> 4;
    int q = tid & 7, rs = tid >> 3;
    int kgq = q >> 1, e4 = (q & 1) * 4;

    for (int k0 = 0; k0 < klen; k0 += 32){
        const unsigned short* Wimg = (const unsigned short*)(Wbase + pblk(pt, k0 >> 7));
        int slab = (k0 & 127) >> 5;
        const unsigned short* hi_img = Wimg + (size_t)(slab*2+0)*4096;
        const unsigned short* lo_img = Wimg + (size_t)(slab*2+1)*4096;
        __syncthreads();
        // A tile: exp only (vc folded into epilogue); frag-order LDS writes
        #pragma unroll
        for (int p = 0; p < 4; p++){
            int row = rs + 32*p;
            float4 dv = *(const float4*)&Arow[(size_t)row*N + k0 + q*4];
            float x0 = __expf(ec*dv.x), x1 = __expf(ec*dv.y);
            float x2 = __expf(ec*dv.z), x3 = __expf(ec*dv.w);
            uint2 hi, lo; split4(x0,x1,x2,x3, hi, lo);
            int u = (row&15) + kgq*16 + ((row>>4)&3)*64 + (row>>6)*256;
            *(uint2*)&Ah[(size_t)u*8 + e4] = hi;
            *(uint2*)&Al[(size_t)u*8 + e4] = lo;
        }
        // B tile: pure 16B copies of pre-split fragment images
        #pragma unroll
        for (int h2 = 0; h2 < 2; h2++){
            int u = tid + h2*256;
            *(uint4*)&Bh[(size_t)u*8] = *(const uint4*)&hi_img[(size_t)u*8];
            *(uint4*)&Bl[(size_t)u*8] = *(const uint4*)&lo_img[(size_t)u*8];
        }
        __syncthreads();
        bf16x8 ah[4], al[4];
        #pragma unroll
        for (int rt=0;rt<4;rt++){
            ah[rt] = *(const bf16x8*)&Ah[((size_t)((wrow*4+rt)*64 + lane))*8];
            al[rt] = *(const bf16x8*)&Al[((size_t)((wrow*4+rt)*64 + lane))*8];
        }
        #pragma unroll
        for (int ct=0;ct<4;ct++){
            bf16x8 bh = *(const bf16x8*)&Bh[((size_t)((wcol*4+ct)*64 + lane))*8];
            bf16x8 bl = *(const bf16x8*)&Bl[((size_t)((wcol*4+ct)*64 + lane))*8];
            #pragma unroll
            for (int rt=0;rt<4;rt++){
                f32x4 a = acc[rt][ct];
                a = __builtin_amdgcn_mfma_f32_16x16x32_bf16(ah[rt], bh, a, 0,0,0);
                a = __builtin_amdgcn_mfma_f32_16x16x32_bf16(ah[rt], bl, a, 0,0,0);
                a = __builtin_amdgcn_mfma_f32_16x16x32_bf16(al[rt], bh, a, 0,0,0);
                acc[rt][ct] = a;
            }
        }
    }
    float vc2 = vc*vc;
    float zv[4];
    #pragma unroll
    for (int ct=0;ct<4;ct++) zv[ct] = zbuf[c*N + pt*NB + wcol*64 + ct*16 + fr];
    #pragma unroll
    for (int rt=0;rt<4;rt++){
        #pragma unroll
        for (int r=0;r<4;r++){
            float m = 0.0f, v = 0.0f;
            #pragma unroll
            for (int ct=0;ct<4;ct++){
                float x = acc[rt][ct][r];
                v += x*x; m += x*zv[ct];
            }
            m += __shfl_xor(m, 1);  v += __shfl_xor(v, 1);
            m += __shfl_xor(m, 2);  v += __shfl_xor(v, 2);
            m += __shfl_xor(m, 4);  v += __shfl_xor(v, 4);
            m += __shfl_xor(m, 8);  v += __shfl_xor(v, 8);
            if (fr == 0){
                int j = jt*NB + wrow*64 + rt*16 + kg*4 + r;
                atomicAdd(&acc_out[j], vc*m);
                atomicAdd(&acc_out[M + j], vc2*v);
            }
        }
    }
}

// ---------------- launch ----------------

extern "C" void kernel_launch(void* const* d_in, const int* in_sizes, int n_in,
                              void* d_out, int out_size, void* d_ws, size_t ws_size,
                              hipStream_t stream) {
    const float* Xtr = (const float*)d_in[0];
    const float* ytr = (const float*)d_in[1];
    const float* Xte = (const float*)d_in[2];
    const float* ls  = (const float*)d_in[3];
    const float* var = (const float*)d_in[4];
    const float* noi = (const float*)d_in[5];
    float* out = (float*)d_out;

    float* ws = (float*)d_ws;
    const size_t shared_fl  = (size_t)N*M + 2*M;                 // d2te + acc
    const size_t perchain   = PL + 2*(size_t)NB*N + (size_t)N;   // L + 2xTrow + z
    size_t avail = ws_size / sizeof(float);
    if (avail < shared_fl + perchain) return;
    int Gmax = (int)((avail - shared_fl) / perchain);
    if (Gmax > 16) Gmax = 16;   // keep widest grid (g x 28) <= 448 co-resident
    if (Gmax > C) Gmax = C;
    int nbatch = (C + Gmax - 1) / Gmax;
    int G = (C + nbatch - 1) / nbatch;          // balanced batches

    float* d2te  = ws;
    float* acc   = d2te + (size_t)N*M;
    float* Lbuf  = acc  + 2*M;
    float* Trow0 = Lbuf + (size_t)G*PL;
    float* Trow1 = Trow0 + (size_t)G*NB*N;
    float* zbuf  = Trow1 + (size_t)G*NB*N;

    k_init_acc<<<dim3((2*M+255)/256), dim3(256), 0, stream>>>(acc);
    k_build_d2te<<<dim3(M), dim3(256), 0, stream>>>(Xtr, Xte, d2te);

    for (int c0 = 0; c0 < C; c0 += G){
        int g = C - c0 < G ? C - c0 : G;

        k_build_K<<<dim3(NBLK, g), dim3(256), 0, stream>>>(Xtr, ls+c0, var+c0, noi+c0, Lbuf, zbuf);

        for (int kb = 0; kb < TB-1; kb++){
            int rem = TB-1-kb;
            k_panel<<<dim3(g, rem), dim3(256), 0, stream>>>(Lbuf, kb);
            k_syrk<<<dim3(g, rem*(rem+1)/2), dim3(256), 0, stream>>>(Lbuf, kb);
        }
        // inversion: gemmA(1) -> fused(1..6) -> gemmB(7); Trow ping-pong by ib parity
        k_gemmA<<<dim3(g, 1), dim3(256), 0, stream>>>(Trow1, Lbuf, 1);
        for (int ib = 1; ib <= 6; ib++){
            float* Trd = (ib & 1) ? Trow1 : Trow0;
            float* Twr = ((ib+1) & 1) ? Trow1 : Trow0;
            k_invAB<<<dim3(g, 2*ib+1), dim3(256), 0, stream>>>(Lbuf, Trd, Twr, ib);
        }
        k_gemmB<<<dim3(g, 7), dim3(256), 0, stream>>>(Lbuf, Trow1, 7);

        k_wsplit<<<dim3(NBLK, g), dim3(256), 0, stream>>>(Lbuf, ytr, zbuf);
        k_bigg<<<dim3(128, g), dim3(256), 0, stream>>>(Lbuf, d2te, zbuf, ls+c0, var+c0, acc);
    }
    k_final<<<dim3((2*M+255)/256), dim3(256), 0, stream>>>(acc, out);
}

// Round 19
// 5484.493 us; speedup vs baseline: 3.5150x; 3.5150x over previous
//
#include <hip/hip_runtime.h>
#include <hip/hip_fp16.h>
#include <math.h>

#define N 1024
#define M 2048
#define C 64
#define NB 128
#define TB 8    // N/NB
#define NBLK 36                   // TB*(TB+1)/2 lower-tri blocks
#define PL ((size_t)NBLK*NB*NB)   // packed L floats per chain

typedef __attribute__((ext_vector_type(8))) short bf16x8;
typedef __attribute__((ext_vector_type(8))) _Float16 f16x8;
typedef __attribute__((ext_vector_type(4))) float f32x4;

__device__ __forceinline__ size_t pblk(int ib, int jt){
    return ((size_t)((ib*(ib+1))/2 + jt))*((size_t)NB*NB);
}

// rotate-swizzle for the in-LDS factor: bank=(r+c)%32
#define TT(r,c) T[(r)][(((c)+(r)) & 127)]

// ---------------- helpers ----------------

__device__ __forceinline__ float sqdist4(const float4 a, const float4 b){
    float dx=a.x-b.x, dy=a.y-b.y, dz=a.z-b.z, dw=a.w-b.w;
    return dx*dx+dy*dy+dz*dz+dw*dw;
}

// split 4 floats into bf16 hi (trunc) + bf16 lo (residual), packed 2/dword
__device__ __forceinline__ void split4(float x0, float x1, float x2, float x3,
                                       uint2& hi, uint2& lo){
    unsigned b0=__float_as_uint(x0), b1=__float_as_uint(x1),
             b2=__float_as_uint(x2), b3=__float_as_uint(x3);
    unsigned h0=b0&0xFFFF0000u, h1=b1&0xFFFF0000u, h2=b2&0xFFFF0000u, h3=b3&0xFFFF0000u;
    hi.x = (h0>>16)|h1;  hi.y = (h2>>16)|h3;
    float l0=x0-__uint_as_float(h0), l1=x1-__uint_as_float(h1),
          l2=x2-__uint_as_float(h2), l3=x3-__uint_as_float(h3);
    lo.x = (__float_as_uint(l0)>>16) | (__float_as_uint(l1)&0xFFFF0000u);
    lo.y = (__float_as_uint(l2)>>16) | (__float_as_uint(l3)&0xFFFF0000u);
}

// Conflict-free in-LDS Cholesky + triangular inversion of a 128x128 block.
__device__ void chol_invert_lds(float T[NB][NB], int tid){
    for (int j = 0; j < NB; j++){
        float d = TT(j,j);
        float inv = 1.0f / sqrtf(d);
        for (int i = j+1+tid; i < NB; i += 256) TT(i,j) *= inv;
        if (tid == 0) TT(j,j) = d * inv;
        __syncthreads();
        int i = j+1 + (tid >> 1);
        if (i < NB){
            float lij = TT(i,j);
            for (int k = j+1+(tid&1); k <= i; k += 2)
                TT(i,k) -= lij * TT(k,j);
        }
        __syncthreads();
    }
    for (int i = 0; i < NB; i++){
        float inv_ii = 1.0f / TT(i,i);
        int j = tid & 127, hi = tid >> 7;
        float S = 0.0f;
        if (j < i){
            for (int k = i-1-hi; k >= j; k -= 2)
                S += TT(i,k) * TT(k,j);
        }
        if (hi && j < i) TT(j,i) = S;
        __syncthreads();
        if (!hi){
            if (j < i)      TT(i,j) = -inv_ii * (S + TT(j,i));
            else if (j == i) TT(i,i) = inv_ii;
        }
        __syncthreads();
    }
}

// ---------------- split-f16 MFMA 128x128x128 GEMM core ----------------

struct FragLds { __half Ah[4096], Al[4096], Bh[4096], Bl[4096]; }; // 32 KiB
struct SmX { float4 xr[NB]; float4 xc[NB]; };                      // 4 KiB
union SmU { FragLds f; float T[NB][NB]; SmX x; };                  // 64 KiB

__device__ __forceinline__ void stage_f16(__half* __restrict__ Hh, __half* __restrict__ Hl,
                                          const float* __restrict__ S, int ld,
                                          int k0, bool contig, int tid){
    #pragma unroll
    for (int h = 0; h < 2; h++){
        int u = tid + h*256;
        int fr = u & 15, kg = (u>>4)&3, rt = (u>>6)&3, hf = u>>8;
        int rc = hf*64 + rt*16 + fr;
        int kk = k0 + kg*8;
        float x[8];
        if (contig){
            float4 v0 = *(const float4*)&S[(size_t)rc*ld + kk];
            float4 v1 = *(const float4*)&S[(size_t)rc*ld + kk + 4];
            x[0]=v0.x;x[1]=v0.y;x[2]=v0.z;x[3]=v0.w;
            x[4]=v1.x;x[5]=v1.y;x[6]=v1.z;x[7]=v1.w;
        } else {
            #pragma unroll
            for (int e=0;e<8;e++) x[e] = S[(size_t)(kk+e)*ld + rc];
        }
        union { __half h[8]; uint4 u4; } Hi, Lo;
        #pragma unroll
        for (int e=0;e<8;e++){
            __half hv = __float2half_rn(x[e]);
            Hi.h[e] = hv;
            Lo.h[e] = __float2half_rn(x[e] - __half2float(hv));
        }
        *(uint4*)&Hh[(size_t)u*8] = Hi.u4;
        *(uint4*)&Hl[(size_t)u*8] = Lo.u4;
    }
}

__device__ __forceinline__ void mfma_slab_f16(const __half* Ah, const __half* Al,
                                              const __half* Bh, const __half* Bl,
                                              int wrow, int wcol, int lane,
                                              f32x4 acc[4][4]){
    f16x8 ah[4], al[4];
    #pragma unroll
    for (int rt=0;rt<4;rt++){
        ah[rt] = *(const f16x8*)&Ah[((size_t)((wrow*4+rt)*64 + lane))*8];
        al[rt] = *(const f16x8*)&Al[((size_t)((wrow*4+rt)*64 + lane))*8];
    }
    #pragma unroll
    for (int ct=0;ct<4;ct++){
        f16x8 bh = *(const f16x8*)&Bh[((size_t)((wcol*4+ct)*64 + lane))*8];
        f16x8 bl = *(const f16x8*)&Bl[((size_t)((wcol*4+ct)*64 + lane))*8];
        #pragma unroll
        for (int rt=0;rt<4;rt++){
            f32x4 a = acc[rt][ct];
            a = __builtin_amdgcn_mfma_f32_16x16x32_f16(ah[rt], bh, a, 0,0,0);
            a = __builtin_amdgcn_mfma_f32_16x16x32_f16(ah[rt], bl, a, 0,0,0);
            a = __builtin_amdgcn_mfma_f32_16x16x32_f16(al[rt], bh, a, 0,0,0);
            acc[rt][ct] = a;
        }
    }
}

__device__ void gemm_f16_unit(const float* __restrict__ A, int lda,
                              const float* __restrict__ B, int ldb, bool bContig,
                              FragLds& F, f32x4 acc[4][4], int tid){
    int lane = tid & 63, w = tid >> 6, wrow = w>>1, wcol = w&1;
    for (int k0 = 0; k0 < NB; k0 += 32){
        __syncthreads();
        stage_f16(F.Ah, F.Al, A, lda, k0, true, tid);
        stage_f16(F.Bh, F.Bl, B, ldb, k0, bContig, tid);
        __syncthreads();
        mfma_slab_f16(F.Ah, F.Al, F.Bh, F.Bl, wrow, wcol, lane, acc);
    }
}

// D-layout store: row = wrow*64+rt*16+kg*4+r, col = wcol*64+ct*16+fr
__device__ __forceinline__ void store_f16acc(float* __restrict__ Cp, int ldc,
                                             const f32x4 acc[4][4], float sgn, int tid){
    int lane = tid&63, w = tid>>6, wrow = w>>1, wcol = w&1;
    int fr = lane&15, kg = lane>>4;
    #pragma unroll
    for (int rt=0;rt<4;rt++)
      #pragma unroll
      for (int ct=0;ct<4;ct++)
        #pragma unroll
        for (int r=0;r<4;r++){
            int row = wrow*64 + rt*16 + kg*4 + r;
            int col = wcol*64 + ct*16 + fr;
            Cp[(size_t)row*ldc + col] = sgn*acc[rt][ct][r];
        }
}

#define ZERO_ACC(acc) { _Pragma("unroll") for (int zi=0;zi<4;zi++) _Pragma("unroll") for (int zj=0;zj<4;zj++) acc[zi][zj] = (f32x4)0.0f; }

// ---------------- kernels ----------------

__global__ void k_init_acc(float* __restrict__ acc){
    int i = blockIdx.x*blockDim.x + threadIdx.x;
    if (i < 2*M) acc[i] = 0.0f;
}

// d2te[j][i] = ||Xte_j - Xtr_i||^2   (M x N)
__global__ void k_build_d2te(const float* __restrict__ Xtr, const float* __restrict__ Xte,
                             float* __restrict__ d2){
    int j = blockIdx.x;
    float4 xj = ((const float4*)Xte)[j];
    for (int i = threadIdx.x; i < N; i += blockDim.x){
        float4 xi = ((const float4*)Xtr)[i];
        d2[(size_t)j*N + i] = sqdist4(xi,xj);
    }
}

__global__ void k_final(const float* __restrict__ acc, float* __restrict__ out){
    int i = blockIdx.x*blockDim.x + threadIdx.x;
    if (i < 2*M) out[i] = acc[i] * (1.0f/64.0f);
}

// Build packed lower-tri blocks of K_noisy. grid (NBLK, g).
// flat==0 block additionally factors+inverts the (0,0) diag block in LDS.
// flat<TB blocks zero their zbuf segment (consumed by k_wsplit's z-dot).
__global__ __launch_bounds__(256) void k_build_K(const float* __restrict__ Xtr,
                          const float* __restrict__ ls,
                          const float* __restrict__ var, const float* __restrict__ noise,
                          float* __restrict__ Lbuf, float* __restrict__ zbuf){
    __shared__ SmU sm;
    int c = blockIdx.y, flat = blockIdx.x;
    int ib = 0; while ((ib+1)*(ib+2)/2 <= flat) ib++;
    int jt = flat - ib*(ib+1)/2;
    int tid = threadIdx.x;
    if (flat < TB && tid < NB) zbuf[c*N + flat*NB + tid] = 0.0f;
    if (tid < NB) sm.x.xr[tid] = ((const float4*)Xtr)[ib*NB + tid];
    else          sm.x.xc[tid-NB] = ((const float4*)Xtr)[jt*NB + (tid-NB)];
    __syncthreads();
    float il2 = 1.0f/(ls[c]*ls[c]);
    float vc = var[c], nc = noise[c];
    float* blk = Lbuf + c*PL + pblk(ib,jt);
    for (int idx = tid; idx < NB*NB; idx += 256){
        int r = idx >> 7, col = idx & 127;
        float d2v = sqdist4(sm.x.xr[r], sm.x.xc[col]);
        float v = vc*__expf(-0.5f*d2v*il2);
        if (ib==jt && r==col) v += nc;
        blk[idx] = v;
    }
    if (flat == 0){
        // block-local global RAW (visible after syncthreads), then factor in LDS
        __threadfence_block();
        __syncthreads();            // xr/xc dead; union reuse as T
        float (*T)[NB] = sm.T;
        for (int idx = tid; idx < NB*NB; idx += 256){
            int r = idx >> 7, col = idx & 127;
            TT(r,col) = blk[idx];
        }
        __syncthreads();
        chol_invert_lds(T, tid);
        for (int idx = tid; idx < NB*NB; idx += 256){
            int r = idx >> 7, col = idx & 127;
            blk[idx] = (col <= r) ? TT(r,col) : 0.0f;
        }
    }
}

// panel TRSM as GEMM: L[ib,kb] = L[ib,kb] @ Dinv_kb^T   (split-f16 MFMA, in place)
__global__ __launch_bounds__(256) void k_panel(float* __restrict__ Lbuf, int kb){
    __shared__ FragLds F;
    int c = blockIdx.x;
    int ib = kb + 1 + blockIdx.y;
    int tid = threadIdx.x;
    float* base = Lbuf + (size_t)c*PL;
    float* Ablk = base + pblk(ib,kb);
    const float* Dv = base + pblk(kb,kb);
    f32x4 acc[4][4]; ZERO_ACC(acc);
    gemm_f16_unit(Ablk, NB, Dv, NB, true, F, acc, tid);   // B[c][k]=Dinv[c][k]
    store_f16acc(Ablk, NB, acc, 1.0f, tid);
}

// trailing update K[i,j] -= P_i @ P_j^T; flat==0 block also factors+inverts
__global__ __launch_bounds__(256) void k_syrk(float* __restrict__ Lbuf, int kb){
    __shared__ SmU sm;
    int c = blockIdx.x;
    int flat = blockIdx.y;
    int di = 0; while ((di+1)*(di+2)/2 <= flat) di++;
    int dj = flat - di*(di+1)/2;
    int i = kb+1+di, j = kb+1+dj;
    int tid = threadIdx.x;
    float* base = Lbuf + (size_t)c*PL;
    float* Cblk = base + pblk(i,j);
    const float* Ablk = base + pblk(i,kb);
    const float* Bblk = base + pblk(j,kb);
    f32x4 acc[4][4]; ZERO_ACC(acc);
    gemm_f16_unit(Ablk, NB, Bblk, NB, true, sm.f, acc, tid);  // B[c][k]=L[j,kb][c][k]
    int lane = tid&63, w = tid>>6, wrow = w>>1, wcol = w&1;
    int fr = lane&15, kg = lane>>4;
    if (flat != 0){
        #pragma unroll
        for (int rt=0;rt<4;rt++)
          #pragma unroll
          for (int ct=0;ct<4;ct++)
            #pragma unroll
            for (int r=0;r<4;r++){
                int row = wrow*64 + rt*16 + kg*4 + r;
                int col = wcol*64 + ct*16 + fr;
                Cblk[(size_t)row*NB + col] -= acc[rt][ct][r];
            }
    } else {
        __syncthreads();   // frag LDS reads done; reuse as T
        float (*T)[NB] = sm.T;
        #pragma unroll
        for (int rt=0;rt<4;rt++)
          #pragma unroll
          for (int ct=0;ct<4;ct++)
            #pragma unroll
            for (int r=0;r<4;r++){
                int row = wrow*64 + rt*16 + kg*4 + r;
                int col = wcol*64 + ct*16 + fr;
                TT(row,col) = Cblk[(size_t)row*NB + col] - acc[rt][ct][r];
            }
        __syncthreads();
        chol_invert_lds(T, tid);
        for (int idx = tid; idx < NB*NB; idx += 256){
            int r = idx >> 7, col = idx & 127;
            Cblk[idx] = (col <= r) ? TT(r,col) : 0.0f;
        }
    }
}

// G(ct) = Dinv_ib @ L[ib,ct]   (snapshot of row ib into Trow; race-free)
__global__ __launch_bounds__(256) void k_gemmA(float* __restrict__ Trow,
                                               const float* __restrict__ Lbuf, int ib){
    __shared__ FragLds F;
    int c = blockIdx.x, ct = blockIdx.y;
    int tid = threadIdx.x;
    const float* base = Lbuf + (size_t)c*PL;
    const float* Dv = base + pblk(ib,ib);
    const float* Bsrc = base + pblk(ib,ct);
    f32x4 acc[4][4]; ZERO_ACC(acc);
    gemm_f16_unit(Dv, NB, Bsrc, NB, false, F, acc, tid);  // B[k][c] strided
    store_f16acc(Trow + (size_t)c*NB*N + ct*NB, N, acc, 1.0f, tid);
}

// W[ib,jt] = - sum_{kt=jt..ib-1} G[:,kt] @ W[kt,jt]   (reads Trow + rows < ib)
__global__ __launch_bounds__(256) void k_gemmB(float* __restrict__ Lbuf,
                                               const float* __restrict__ Trow, int ib){
    __shared__ FragLds F;
    int c = blockIdx.x, jt = blockIdx.y;
    int tid = threadIdx.x;
    const float* G = Trow + (size_t)c*NB*N;
    float* base = Lbuf + (size_t)c*PL;
    f32x4 acc[4][4]; ZERO_ACC(acc);
    for (int kt = jt; kt < ib; kt++)
        gemm_f16_unit(G + kt*NB, N, base + pblk(kt,jt), NB, false, F, acc, tid);
    store_f16acc(base + pblk(ib,jt), NB, acc, -1.0f, tid);
}

// Per W block: (1) z-partial: z[pb*128+row] += W_block_row . y[kt*128..]
// (full 128-wide dot is exact: diag blocks store zero upper), then
// (2) convert block IN PLACE to fragment-order split-bf16 images
// [slab 0..3][hi/lo][512 units][8 shorts].
__global__ __launch_bounds__(256) void k_wsplit(float* __restrict__ Lbuf,
                                                const float* __restrict__ ytr,
                                                float* __restrict__ zbuf){
    int c = blockIdx.y, flat = blockIdx.x;
    int pb = 0; while ((pb+1)*(pb+2)/2 <= flat) pb++;
    int kt = flat - pb*(pb+1)/2;
    int tid = threadIdx.x;
    float* blk = Lbuf + c*PL + (size_t)flat*NB*NB;
    // --- z-dot (reads f32 block before overwrite) ---
    {
        int row = tid >> 1, half = tid & 1;
        const float* wp = blk + (size_t)row*NB + half*64;
        const float* yp = ytr + kt*NB + half*64;
        float s = 0.0f;
        for (int i = 0; i < 64; i++) s += wp[i]*yp[i];
        s += __shfl_xor(s, 1);
        if (!half) atomicAdd(&zbuf[c*N + pb*NB + row], s);
    }
    // --- in-place split (register staged; barrier separates reads/writes) ---
    float4 v[16];
    #pragma unroll
    for (int h = 0; h < 8; h++){
        int g = tid + h*256;           // unit-global 0..2047
        int u = g & 511, slab = g >> 9;
        int fr = u&15, kg = (u>>4)&3, rt = (u>>6)&3, hf = u>>8;
        int row = hf*64 + rt*16 + fr;
        int k = slab*32 + kg*8;
        v[2*h]   = *(const float4*)&blk[(size_t)row*NB + k];
        v[2*h+1] = *(const float4*)&blk[(size_t)row*NB + k + 4];
    }
    __syncthreads();
    unsigned short* out = (unsigned short*)blk;
    #pragma unroll
    for (int h = 0; h < 8; h++){
        int g = tid + h*256;
        int u = g & 511, slab = g >> 9;
        uint2 h0, l0, h1, l1;
        split4(v[2*h].x, v[2*h].y, v[2*h].z, v[2*h].w, h0, l0);
        split4(v[2*h+1].x, v[2*h+1].y, v[2*h+1].z, v[2*h+1].w, h1, l1);
        *(uint4*)&out[((size_t)(slab*2+0)*512 + u)*8] = make_uint4(h0.x,h0.y,h1.x,h1.y);
        *(uint4*)&out[((size_t)(slab*2+1)*512 + u)*8] = make_uint4(l0.x,l0.y,l1.x,l1.y);
    }
}

// Fused A = Kte @ W^T via split-bf16 MFMA.  A: exp-only staging to LDS
// (vc folded into epilogue); B: coalesced 16B LDS copies of pre-split
// fragment images.  Grid x = 128 flat (jt,pt):
//   jt = flat&15, pt = ((flat>>4) + (jt&7)) & 7
// acc_out[0..M)=mean, [M..2M)=var.
__global__ __launch_bounds__(256) void k_bigg(const float* __restrict__ Lbuf,
                                              const float* __restrict__ d2,   // [M][N]
                                              const float* __restrict__ zbuf,
                                              const float* __restrict__ ls,
                                              const float* __restrict__ var,
                                              float* __restrict__ acc_out){
    __shared__ unsigned short Ah[4096], Al[4096], Bh[4096], Bl[4096];  // 32 KiB
    int flat = blockIdx.x, c = blockIdx.y;
    int jt = flat & 15;
    int pt = ((flat >> 4) + (jt & 7)) & 7;
    int tid = threadIdx.x;
    int lane = tid & 63, w = tid >> 6;
    int wrow = w >> 1, wcol = w & 1;
    float il2 = 1.0f/(ls[c]*ls[c]);
    float vc = var[c];
    float ec = -0.5f*il2;
    const float* Arow = d2 + (size_t)(jt*NB)*N;
    const float* Wbase = Lbuf + (size_t)c*PL;
    int klen = (pt+1)*NB;
    f32x4 acc[4][4]; ZERO_ACC(acc);

    int fr = lane & 15, kg = lane >> 4;
    int q = tid & 7, rs = tid >> 3;
    int kgq = q >> 1, e4 = (q & 1) * 4;

    for (int k0 = 0; k0 < klen; k0 += 32){
        const unsigned short* Wimg = (const unsigned short*)(Wbase + pblk(pt, k0 >> 7));
        int slab = (k0 & 127) >> 5;
        const unsigned short* hi_img = Wimg + (size_t)(slab*2+0)*4096;
        const unsigned short* lo_img = Wimg + (size_t)(slab*2+1)*4096;
        __syncthreads();
        // A tile: exp only (vc folded into epilogue); frag-order LDS writes
        #pragma unroll
        for (int p = 0; p < 4; p++){
            int row = rs + 32*p;
            float4 dv = *(const float4*)&Arow[(size_t)row*N + k0 + q*4];
            float x0 = __expf(ec*dv.x), x1 = __expf(ec*dv.y);
            float x2 = __expf(ec*dv.z), x3 = __expf(ec*dv.w);
            uint2 hi, lo; split4(x0,x1,x2,x3, hi, lo);
            int u = (row&15) + kgq*16 + ((row>>4)&3)*64 + (row>>6)*256;
            *(uint2*)&Ah[(size_t)u*8 + e4] = hi;
            *(uint2*)&Al[(size_t)u*8 + e4] = lo;
        }
        // B tile: pure 16B copies of pre-split fragment images
        #pragma unroll
        for (int h2 = 0; h2 < 2; h2++){
            int u = tid + h2*256;
            *(uint4*)&Bh[(size_t)u*8] = *(const uint4*)&hi_img[(size_t)u*8];
            *(uint4*)&Bl[(size_t)u*8] = *(const uint4*)&lo_img[(size_t)u*8];
        }
        __syncthreads();
        bf16x8 ah[4], al[4];
        #pragma unroll
        for (int rt=0;rt<4;rt++){
            ah[rt] = *(const bf16x8*)&Ah[((size_t)((wrow*4+rt)*64 + lane))*8];
            al[rt] = *(const bf16x8*)&Al[((size_t)((wrow*4+rt)*64 + lane))*8];
        }
        #pragma unroll
        for (int ct=0;ct<4;ct++){
            bf16x8 bh = *(const bf16x8*)&Bh[((size_t)((wcol*4+ct)*64 + lane))*8];
            bf16x8 bl = *(const bf16x8*)&Bl[((size_t)((wcol*4+ct)*64 + lane))*8];
            #pragma unroll
            for (int rt=0;rt<4;rt++){
                f32x4 a = acc[rt][ct];
                a = __builtin_amdgcn_mfma_f32_16x16x32_bf16(ah[rt], bh, a, 0,0,0);
                a = __builtin_amdgcn_mfma_f32_16x16x32_bf16(ah[rt], bl, a, 0,0,0);
                a = __builtin_amdgcn_mfma_f32_16x16x32_bf16(al[rt], bh, a, 0,0,0);
                acc[rt][ct] = a;
            }
        }
    }
    float vc2 = vc*vc;
    float zv[4];
    #pragma unroll
    for (int ct=0;ct<4;ct++) zv[ct] = zbuf[c*N + pt*NB + wcol*64 + ct*16 + fr];
    #pragma unroll
    for (int rt=0;rt<4;rt++){
        #pragma unroll
        for (int r=0;r<4;r++){
            float m = 0.0f, v = 0.0f;
            #pragma unroll
            for (int ct=0;ct<4;ct++){
                float x = acc[rt][ct][r];
                v += x*x; m += x*zv[ct];
            }
            m += __shfl_xor(m, 1);  v += __shfl_xor(v, 1);
            m += __shfl_xor(m, 2);  v += __shfl_xor(v, 2);
            m += __shfl_xor(m, 4);  v += __shfl_xor(v, 4);
            m += __shfl_xor(m, 8);  v += __shfl_xor(v, 8);
            if (fr == 0){
                int j = jt*NB + wrow*64 + rt*16 + kg*4 + r;
                atomicAdd(&acc_out[j], vc*m);
                atomicAdd(&acc_out[M + j], vc2*v);
            }
        }
    }
}

// ---------------- launch ----------------

extern "C" void kernel_launch(void* const* d_in, const int* in_sizes, int n_in,
                              void* d_out, int out_size, void* d_ws, size_t ws_size,
                              hipStream_t stream) {
    const float* Xtr = (const float*)d_in[0];
    const float* ytr = (const float*)d_in[1];
    const float* Xte = (const float*)d_in[2];
    const float* ls  = (const float*)d_in[3];
    const float* var = (const float*)d_in[4];
    const float* noi = (const float*)d_in[5];
    float* out = (float*)d_out;

    float* ws = (float*)d_ws;
    const size_t shared_fl  = (size_t)N*M + 2*M;              // d2te + acc
    const size_t perchain   = PL + (size_t)NB*N + (size_t)N;  // L + Trow + z
    size_t avail = ws_size / sizeof(float);
    if (avail < shared_fl + perchain) return;
    int Gmax = (int)((avail - shared_fl) / perchain);
    if (Gmax > C) Gmax = C;
    int nbatch = (C + Gmax - 1) / Gmax;
    int G = (C + nbatch - 1) / nbatch;          // balanced batches

    float* d2te = ws;
    float* acc  = d2te + (size_t)N*M;
    float* Lbuf = acc  + 2*M;
    float* Trow = Lbuf + (size_t)G*PL;
    float* zbuf = Trow + (size_t)G*NB*N;

    k_init_acc<<<dim3((2*M+255)/256), dim3(256), 0, stream>>>(acc);
    k_build_d2te<<<dim3(M), dim3(256), 0, stream>>>(Xtr, Xte, d2te);

    for (int c0 = 0; c0 < C; c0 += G){
        int g = C - c0 < G ? C - c0 : G;

        k_build_K<<<dim3(NBLK, g), dim3(256), 0, stream>>>(Xtr, ls+c0, var+c0, noi+c0, Lbuf, zbuf);

        for (int kb = 0; kb < TB-1; kb++){
            int rem = TB-1-kb;
            k_panel<<<dim3(g, rem), dim3(256), 0, stream>>>(Lbuf, kb);
            k_syrk<<<dim3(g, rem*(rem+1)/2), dim3(256), 0, stream>>>(Lbuf, kb);
        }
        for (int ib = 1; ib < TB; ib++){
            k_gemmA<<<dim3(g, ib), dim3(256), 0, stream>>>(Trow, Lbuf, ib);
            k_gemmB<<<dim3(g, ib), dim3(256), 0, stream>>>(Lbuf, Trow, ib);
        }
        k_wsplit<<<dim3(NBLK, g), dim3(256), 0, stream>>>(Lbuf, ytr, zbuf);
        k_bigg<<<dim3(128, g), dim3(256), 0, stream>>>(Lbuf, d2te, zbuf, ls+c0, var+c0, acc);
    }
    k_final<<<dim3((2*M+255)/256), dim3(256), 0, stream>>>(acc, out);
}